// Round 2
// baseline (1358.232 us; speedup 1.0000x reference)
//
#include <hip/hip_runtime.h>
#include <cstddef>

#define N_NODES 50000
#define N_EDGES 800000
#define N_PAIRS 100000

typedef short short8 __attribute__((ext_vector_type(8)));
typedef float floatx4 __attribute__((ext_vector_type(4)));
typedef unsigned short ushort_t;

__device__ inline ushort_t f2bf(float x) {
  unsigned u = __float_as_uint(x);
  u += 0x7FFF + ((u >> 16) & 1);   // RNE
  return (ushort_t)(u >> 16);
}
__device__ inline float bf2f(ushort_t h) {
  return __uint_as_float(((unsigned)h) << 16);
}

// ---------------- weight folding: Wcat[l] = [Wk@att*pri/4 | Wq | Wv@msg], 128x384 per layer (fp32)
__global__ void fold_weights_kernel(const float* __restrict__ Wk,
                                    const float* __restrict__ Wq,
                                    const float* __restrict__ Wv,
                                    const float* __restrict__ att,
                                    const float* __restrict__ msg,
                                    const float* __restrict__ pri,
                                    float* __restrict__ Wcat) {
  int gid = blockIdx.x * blockDim.x + threadIdx.x;
  const int total = 3 * 128 * 384;
  if (gid >= total) return;
  int l = gid / (128 * 384);
  int rem = gid - l * (128 * 384);
  int r = rem / 384;
  int j = rem - r * 384;
  float out;
  if (j >= 128 && j < 256) {
    out = Wq[(l * 128 + r) * 128 + (j - 128)];
  } else {
    int jj = j & 127;
    int hh = jj >> 4;
    int e = jj & 15;
    const float* W = (j < 128) ? Wk : Wv;
    const float* T = (j < 128) ? att : msg;
    float s = 0.f;
#pragma unroll
    for (int d = 0; d < 16; d++)
      s += W[(l * 128 + r) * 128 + hh * 16 + d] * T[((l * 8 + hh) * 16 + d) * 16 + e];
    if (j < 128) s *= pri[l * 8 + hh] * 0.25f;  // pri / sqrt(D=16)
    out = s;
  }
  Wcat[gid] = out;
}

// ---------------- transpose+split weights: W fp32 [K][N] -> Bt hi/lo bf16 [Npad][K]
__global__ void prep_bt_kernel(const float* __restrict__ W, ushort_t* __restrict__ Bh,
                               ushort_t* __restrict__ Bl, int K, int N, int Npad) {
  int g = blockIdx.x * blockDim.x + threadIdx.x;
  if (g >= Npad * K) return;
  int n = g / K, k = g - n * K;
  float v = (n < N) ? W[(size_t)k * N + n] : 0.f;
  ushort_t hh = f2bf(v);
  Bh[g] = hh;
  Bl[g] = f2bf(v - bf2f(hh));
}

// ---------------- split fp32 matrix into bf16 hi/lo
__global__ void split_mat_kernel(const float* __restrict__ X, ushort_t* __restrict__ Xh,
                                 ushort_t* __restrict__ Xl, int total) {
  int g = blockIdx.x * blockDim.x + threadIdx.x;
  if (g >= total) return;
  float v = X[g];
  ushort_t hh = f2bf(v);
  Xh[g] = hh;
  Xl[g] = f2bf(v - bf2f(hh));
}

// ---------------- CSR build by destination
__global__ void hist_kernel(const int* __restrict__ dst, int* __restrict__ deg, int E) {
  int g = blockIdx.x * blockDim.x + threadIdx.x;
  if (g < E) atomicAdd(&deg[dst[g]], 1);
}

__global__ void scan_kernel(const int* __restrict__ deg, int* __restrict__ offs,
                            int* __restrict__ cursor, int n) {
  __shared__ int sums[256];
  int t = threadIdx.x;
  int chunk = (n + 255) / 256;
  int begin = min(t * chunk, n);
  int end = min(begin + chunk, n);
  int s = 0;
  for (int i = begin; i < end; i++) s += deg[i];
  sums[t] = s;
  __syncthreads();
  for (int off = 1; off < 256; off <<= 1) {
    int v = (t >= off) ? sums[t - off] : 0;
    __syncthreads();
    sums[t] += v;
    __syncthreads();
  }
  int run = sums[t] - s;
  for (int i = begin; i < end; i++) {
    offs[i] = run;
    cursor[i] = run;
    run += deg[i];
  }
  if (t == 255) offs[n] = sums[255];
}

__global__ void scatter_kernel(const int* __restrict__ src, const int* __restrict__ dst,
                               const float* __restrict__ w, int* __restrict__ cursor,
                               int* __restrict__ elsrc, float* __restrict__ elw, int E) {
  int g = blockIdx.x * blockDim.x + threadIdx.x;
  if (g < E) {
    int d = dst[g];
    int p = atomicAdd(&cursor[d], 1);
    elsrc[p] = src[g];
    elw[p] = w[g];
  }
}

// ---------------- split-bf16 MFMA GEMM: C = A@B (+epilogue)
// A: hi/lo bf16 [M][K]; Bt: hi/lo bf16 [Npad][K] (pre-transposed)
// wave computes 64x64 tile; block = 4 waves = 256 rows strip
// epi: 0 bias+relu, 1 plain, 2 skip-mix(+relu opt), 3 bias+leaky(0.2)
__global__ __launch_bounds__(256) void gemm_mfma(
    const ushort_t* __restrict__ Ah, const ushort_t* __restrict__ Al,
    const ushort_t* __restrict__ Bth, const ushort_t* __restrict__ Btl,
    int M, int N, int K, int epi,
    const float* __restrict__ bias, const float* __restrict__ hold,
    const float* __restrict__ skipv, int relu,
    float* __restrict__ Cf, ushort_t* __restrict__ Chi, ushort_t* __restrict__ Clo) {
  int tid = threadIdx.x;
  int wave = tid >> 6, lane = tid & 63;
  int l16 = lane & 15, q = lane >> 4;
  int m_base = blockIdx.x * 256 + wave * 64;
  int n_base = blockIdx.y * 64;

  floatx4 acc[4][4];
#pragma unroll
  for (int i = 0; i < 4; i++)
#pragma unroll
    for (int j = 0; j < 4; j++) acc[i][j] = (floatx4){0.f, 0.f, 0.f, 0.f};

  size_t arow[4];
  bool rv[4];
#pragma unroll
  for (int mt = 0; mt < 4; mt++) {
    int r = m_base + mt * 16 + l16;
    rv[mt] = r < M;
    arow[mt] = (size_t)(rv[mt] ? r : 0) * K;
  }
  size_t brow[4];
#pragma unroll
  for (int nt = 0; nt < 4; nt++) brow[nt] = (size_t)(n_base + nt * 16 + l16) * K;

  const short8 zer = {0, 0, 0, 0, 0, 0, 0, 0};
  for (int k0 = 0; k0 < K; k0 += 32) {
    int ko = k0 + q * 8;
    short8 a_h[4], a_l[4], b_h[4], b_l[4];
#pragma unroll
    for (int nt = 0; nt < 4; nt++) {
      b_h[nt] = *(const short8*)(Bth + brow[nt] + ko);
      b_l[nt] = *(const short8*)(Btl + brow[nt] + ko);
    }
#pragma unroll
    for (int mt = 0; mt < 4; mt++) {
      if (rv[mt]) {
        a_h[mt] = *(const short8*)(Ah + arow[mt] + ko);
        a_l[mt] = *(const short8*)(Al + arow[mt] + ko);
      } else {
        a_h[mt] = zer;
        a_l[mt] = zer;
      }
    }
#pragma unroll
    for (int mt = 0; mt < 4; mt++)
#pragma unroll
      for (int nt = 0; nt < 4; nt++) {
        acc[mt][nt] = __builtin_amdgcn_mfma_f32_16x16x32_bf16(a_h[mt], b_h[nt], acc[mt][nt], 0, 0, 0);
        acc[mt][nt] = __builtin_amdgcn_mfma_f32_16x16x32_bf16(a_h[mt], b_l[nt], acc[mt][nt], 0, 0, 0);
        acc[mt][nt] = __builtin_amdgcn_mfma_f32_16x16x32_bf16(a_l[mt], b_h[nt], acc[mt][nt], 0, 0, 0);
      }
  }

  float alpha = 1.f, beta = 0.f;
  if (epi == 2) {
    float s = *skipv;
    alpha = 1.f / (1.f + __expf(-s));
    beta = 1.f - alpha;
  }
#pragma unroll
  for (int mt = 0; mt < 4; mt++) {
#pragma unroll
    for (int nt = 0; nt < 4; nt++) {
      int col = n_base + nt * 16 + l16;
      if (col >= N) continue;
      float bv = (epi == 0 || epi == 3) ? bias[col] : 0.f;
#pragma unroll
      for (int r = 0; r < 4; r++) {
        int row = m_base + mt * 16 + q * 4 + r;
        if (row >= M) continue;
        float v = acc[mt][nt][r];
        if (epi == 0) {
          v = fmaxf(v + bv, 0.f);
        } else if (epi == 2) {
          v = alpha * v + beta * hold[(size_t)row * N + col];
          if (relu) v = fmaxf(v, 0.f);
        } else if (epi == 3) {
          v += bv;
          v = v > 0.f ? v : 0.2f * v;
        }
        size_t idx = (size_t)row * N + col;
        if (Cf) Cf[idx] = v;
        if (Chi) {
          ushort_t hh = f2bf(v);
          Chi[idx] = hh;
          Clo[idx] = f2bf(v - bf2f(hh));
        }
      }
    }
  }
}

// ---------------- per-destination online-softmax aggregation (float4 gathers)
// one wave per node; lane c in [0,32) covers channels 4c..4c+3; half = lane>>5 (0: kw, 1: mv)
__global__ __launch_bounds__(256) void edge_agg_kernel(
    const float* __restrict__ kqv, const int* __restrict__ offs,
    const int* __restrict__ elsrc, const float* __restrict__ elw,
    ushort_t* __restrict__ agg_hi, ushort_t* __restrict__ agg_lo, int n) {
  int wave = threadIdx.x >> 6;
  int lane = threadIdx.x & 63;
  int node = blockIdx.x * 4 + wave;
  if (node >= n) return;
  int c2 = lane & 31, half = lane >> 5;
  int ch = c2 * 4;
  float4 qv = *(const float4*)&kqv[(size_t)node * 384 + 128 + ch];
  size_t off_half = (size_t)(half ? 256 : 0) + ch;
  float m = -1e30f, s = 0.f;
  float ax = 0.f, ay = 0.f, az = 0.f, aw = 0.f;
  int beg = offs[node], end = offs[node + 1];
  for (int j = beg; j < end; j++) {
    int si = elsrc[j];
    float w = elw[j];
    float4 g = *(const float4*)&kqv[(size_t)si * 384 + off_half];
    float p = g.x * qv.x + g.y * qv.y + g.z * qv.z + g.w * qv.w;  // valid on kw half
    p += __shfl_xor(p, 1);
    p += __shfl_xor(p, 2);
    float po = __shfl_xor(p, 32);
    if (half) p = po;  // mv lanes receive their head's logit
    float nm = fmaxf(m, p);
    float sc = __expf(m - nm);
    float e = __expf(p - nm);
    s = s * sc + e;
    m = nm;
    if (half) {
      float ew = e * w;
      ax = ax * sc + ew * g.x;
      ay = ay * sc + ew * g.y;
      az = az * sc + ew * g.z;
      aw = aw * sc + ew * g.w;
    }
  }
  if (half) {
    float inv = (s > 0.f) ? 1.f / s : 0.f;
    float v0 = ax * inv, v1 = ay * inv, v2 = az * inv, v3 = aw * inv;
    ushort_t h0 = f2bf(v0), h1 = f2bf(v1), h2 = f2bf(v2), h3 = f2bf(v3);
    uint2 vh = make_uint2((unsigned)h0 | ((unsigned)h1 << 16),
                          (unsigned)h2 | ((unsigned)h3 << 16));
    *(uint2*)(agg_hi + (size_t)node * 128 + ch) = vh;
    ushort_t l0 = f2bf(v0 - bf2f(h0)), l1 = f2bf(v1 - bf2f(h1));
    ushort_t l2 = f2bf(v2 - bf2f(h2)), l3 = f2bf(v3 - bf2f(h3));
    uint2 vl = make_uint2((unsigned)l0 | ((unsigned)l1 << 16),
                          (unsigned)l2 | ((unsigned)l3 << 16));
    *(uint2*)(agg_lo + (size_t)node * 128 + ch) = vl;
  }
}

// ---------------- predictor helpers
__global__ void zbuild_kernel(const float* __restrict__ hsrc, const int* __restrict__ ia,
                              const int* __restrict__ ib, ushort_t* __restrict__ Zh,
                              ushort_t* __restrict__ Zl, int P) {
  int g = blockIdx.x * blockDim.x + threadIdx.x;
  if (g >= P * 32) return;
  int r = g >> 5, c = (g & 31) << 2;
  float4 va = *(const float4*)&hsrc[(size_t)ia[r] * 128 + c];
  float4 vb = *(const float4*)&hsrc[(size_t)ib[r] * 128 + c];
  float z0 = va.x * vb.x, z1 = va.y * vb.y, z2 = va.z * vb.z, z3 = va.w * vb.w;
  ushort_t h0 = f2bf(z0), h1 = f2bf(z1), h2 = f2bf(z2), h3 = f2bf(z3);
  *(uint2*)(Zh + (size_t)r * 128 + c) =
      make_uint2((unsigned)h0 | ((unsigned)h1 << 16), (unsigned)h2 | ((unsigned)h3 << 16));
  ushort_t l0 = f2bf(z0 - bf2f(h0)), l1 = f2bf(z1 - bf2f(h1));
  ushort_t l2 = f2bf(z2 - bf2f(h2)), l3 = f2bf(z3 - bf2f(h3));
  *(uint2*)(Zl + (size_t)r * 128 + c) =
      make_uint2((unsigned)l0 | ((unsigned)l1 << 16), (unsigned)l2 | ((unsigned)l3 << 16));
}

__global__ void final_dot_kernel(const float* __restrict__ T2, const float* __restrict__ W3,
                                 const float* __restrict__ b3, float* __restrict__ outp, int P) {
  int r = blockIdx.x * blockDim.x + threadIdx.x;
  if (r >= P) return;
  float acc = b3[0];
  const float* row = T2 + (size_t)r * 32;
#pragma unroll
  for (int k = 0; k < 32; k++) acc += row[k] * W3[k];
  outp[r] = acc;
}

extern "C" void kernel_launch(void* const* d_in, const int* in_sizes, int n_in,
                              void* d_out, int out_size, void* d_ws, size_t ws_size,
                              hipStream_t stream) {
  const float* x        = (const float*)d_in[0];
  const int*   edge_src = (const int*)d_in[1];
  const int*   edge_dst = (const int*)d_in[2];
  const float* edge_w   = (const float*)d_in[3];
  const int*   pos_src  = (const int*)d_in[4];
  const int*   pos_dst  = (const int*)d_in[5];
  const int*   neg_src  = (const int*)d_in[6];
  const int*   neg_dst  = (const int*)d_in[7];
  const float* W_in     = (const float*)d_in[8];
  const float* b_in     = (const float*)d_in[9];
  const float* Wk       = (const float*)d_in[10];
  const float* Wq       = (const float*)d_in[11];
  const float* Wv       = (const float*)d_in[12];
  const float* att_w    = (const float*)d_in[13];
  const float* msg_w    = (const float*)d_in[14];
  const float* pri      = (const float*)d_in[15];
  const float* Wa       = (const float*)d_in[16];
  const float* skip     = (const float*)d_in[17];
  const float* W1       = (const float*)d_in[18];
  const float* b1       = (const float*)d_in[19];
  const float* W2       = (const float*)d_in[20];
  const float* b2       = (const float*)d_in[21];
  const float* W3       = (const float*)d_in[22];
  const float* b3       = (const float*)d_in[23];
  float* out = (float*)d_out;

  // ---- workspace layout (bytes), ~162 MB, heavy aliasing
  char* W = (char*)d_ws;
  float*    kqv    = (float*)(W + 0);              // 76,800,000
  float*    h      = (float*)(W + 76800000);       // 25,600,000
  ushort_t* h_hi   = (ushort_t*)(W + 102400000);   // 12,800,000
  ushort_t* h_lo   = (ushort_t*)(W + 115200000);   // 12,800,000
  ushort_t* s1_hi  = (ushort_t*)(W + 128000000);   // 12,800,000 (x_hi -> agg_hi -> T1_hi)
  ushort_t* s1_lo  = (ushort_t*)(W + 140800000);   // 12,800,000
  float*    Wcat   = (float*)(W + 153600000);      // 589,824
  ushort_t* Wint_h = (ushort_t*)(W + 154189824);   // 32,768
  ushort_t* Wint_l = (ushort_t*)(W + 154222592);   // 32,768
  ushort_t* Wcat_h = (ushort_t*)(W + 154255360);   // 294,912
  ushort_t* Wcat_l = (ushort_t*)(W + 154550272);   // 294,912
  ushort_t* Wa_h   = (ushort_t*)(W + 154845184);   // 98,304
  ushort_t* Wa_l   = (ushort_t*)(W + 154943488);   // 98,304
  ushort_t* W1_h   = (ushort_t*)(W + 155041792);   // 16,384
  ushort_t* W1_l   = (ushort_t*)(W + 155058176);   // 16,384
  ushort_t* W2_h   = (ushort_t*)(W + 155074560);   // 8,192
  ushort_t* W2_l   = (ushort_t*)(W + 155082752);   // 8,192
  float*    elw    = (float*)(W + 155100000);      // 3,200,000
  int*      elsrc  = (int*)(W + 158300000);        // 3,200,000
  int*      deg    = (int*)(W + 161500000);        // 200,000
  int*      offs   = (int*)(W + 161700000);        // 200,016
  int*      cursor = (int*)(W + 161900016);        // 200,000
  // aliases
  ushort_t* Z_h  = (ushort_t*)(W + 0);             // 25,600,000 (over kqv, dead by predictor)
  ushort_t* Z_l  = (ushort_t*)(W + 25600000);      // 25,600,000
  float*    T2   = h;                              // 12,800,000 (h dead by predictor)
  ushort_t* agg_hi = s1_hi; ushort_t* agg_lo = s1_lo;
  ushort_t* T1_h = s1_hi;  ushort_t* T1_l = s1_lo;
  float* hfinal = out + 2 * N_PAIRS;

  hipMemsetAsync(deg, 0, N_NODES * sizeof(int), stream);
  fold_weights_kernel<<<(3 * 128 * 384 + 255) / 256, 256, 0, stream>>>(
      Wk, Wq, Wv, att_w, msg_w, pri, Wcat);
  // weight transpose+split
  prep_bt_kernel<<<(128 * 128 + 255) / 256, 256, 0, stream>>>(W_in, Wint_h, Wint_l, 128, 128, 128);
  for (int l = 0; l < 3; l++) {
    prep_bt_kernel<<<(384 * 128 + 255) / 256, 256, 0, stream>>>(
        Wcat + l * 49152, Wcat_h + l * 49152, Wcat_l + l * 49152, 128, 384, 384);
    prep_bt_kernel<<<(128 * 128 + 255) / 256, 256, 0, stream>>>(
        Wa + l * 16384, Wa_h + l * 16384, Wa_l + l * 16384, 128, 128, 128);
  }
  prep_bt_kernel<<<(64 * 128 + 255) / 256, 256, 0, stream>>>(W1, W1_h, W1_l, 128, 64, 64);
  prep_bt_kernel<<<(64 * 64 + 255) / 256, 256, 0, stream>>>(W2, W2_h, W2_l, 64, 32, 64);
  // x split (s1 reused as agg later; input GEMM consumes x first)
  split_mat_kernel<<<(N_NODES * 128 + 255) / 256, 256, 0, stream>>>(x, s1_hi, s1_lo, N_NODES * 128);
  // CSR
  hist_kernel<<<(N_EDGES + 255) / 256, 256, 0, stream>>>(edge_dst, deg, N_EDGES);
  scan_kernel<<<1, 256, 0, stream>>>(deg, offs, cursor, N_NODES);
  scatter_kernel<<<(N_EDGES + 255) / 256, 256, 0, stream>>>(
      edge_src, edge_dst, edge_w, cursor, elsrc, elw, N_EDGES);

  // input projection: h = relu(x @ W_in + b_in), emit fp32 + hi/lo
  gemm_mfma<<<dim3(196, 2), 256, 0, stream>>>(s1_hi, s1_lo, Wint_h, Wint_l,
                                              N_NODES, 128, 128, 0,
                                              b_in, nullptr, nullptr, 0,
                                              h, h_hi, h_lo);

  for (int l = 0; l < 3; l++) {
    gemm_mfma<<<dim3(196, 6), 256, 0, stream>>>(h_hi, h_lo,
                                                Wcat_h + l * 49152, Wcat_l + l * 49152,
                                                N_NODES, 384, 128, 1,
                                                nullptr, nullptr, nullptr, 0,
                                                kqv, nullptr, nullptr);
    edge_agg_kernel<<<(N_NODES + 3) / 4, 256, 0, stream>>>(kqv, offs, elsrc, elw,
                                                           agg_hi, agg_lo, N_NODES);
    int last = (l == 2);
    gemm_mfma<<<dim3(196, 2), 256, 0, stream>>>(agg_hi, agg_lo,
                                                Wa_h + l * 16384, Wa_l + l * 16384,
                                                N_NODES, 128, 128, 2,
                                                nullptr, h, skip + l, last ? 0 : 1,
                                                last ? hfinal : h,
                                                last ? nullptr : h_hi,
                                                last ? nullptr : h_lo);
  }

  for (int half = 0; half < 2; half++) {
    const int* ia = half ? neg_src : pos_src;
    const int* ib = half ? neg_dst : pos_dst;
    zbuild_kernel<<<(N_PAIRS * 32 + 255) / 256, 256, 0, stream>>>(hfinal, ia, ib,
                                                                  Z_h, Z_l, N_PAIRS);
    gemm_mfma<<<dim3(391, 1), 256, 0, stream>>>(Z_h, Z_l, W1_h, W1_l,
                                                N_PAIRS, 64, 128, 3,
                                                b1, nullptr, nullptr, 0,
                                                nullptr, T1_h, T1_l);
    gemm_mfma<<<dim3(391, 1), 256, 0, stream>>>(T1_h, T1_l, W2_h, W2_l,
                                                N_PAIRS, 32, 64, 3,
                                                b2, nullptr, nullptr, 0,
                                                T2, nullptr, nullptr);
    final_dot_kernel<<<(N_PAIRS + 255) / 256, 256, 0, stream>>>(
        T2, W3, b3, out + half * N_PAIRS, N_PAIRS);
  }
}

// Round 3
// 1165.897 us; speedup vs baseline: 1.1650x; 1.1650x over previous
//
#include <hip/hip_runtime.h>
#include <cstddef>

#define N_NODES 50000
#define N_EDGES 800000
#define N_PAIRS 100000

typedef short short8 __attribute__((ext_vector_type(8)));
typedef float floatx4 __attribute__((ext_vector_type(4)));
typedef unsigned short ushort_t;

__device__ inline ushort_t f2bf(float x) {
  unsigned u = __float_as_uint(x);
  u += 0x7FFF + ((u >> 16) & 1);   // RNE
  return (ushort_t)(u >> 16);
}
__device__ inline float bf2f(ushort_t h) {
  return __uint_as_float(((unsigned)h) << 16);
}
// packed MFMA A/B-fragment layout: [tile16][kchunk32][lane][8]
// lane = ((k>>3)&3)*16 + (m&15), elem j = k&7
__device__ inline size_t packA(int m, int k, int K) {
  return ((size_t)((m >> 4) * (K >> 5) + (k >> 5)) << 9) +
         ((((unsigned)k >> 3) & 3) << 7) + ((m & 15) << 3) + (k & 7);
}

// ---------------- weight folding: Wcat[l] = [Wk@att*pri/4 | Wq | Wv@msg], 128x384 per layer (fp32)
__global__ void fold_weights_kernel(const float* __restrict__ Wk,
                                    const float* __restrict__ Wq,
                                    const float* __restrict__ Wv,
                                    const float* __restrict__ att,
                                    const float* __restrict__ msg,
                                    const float* __restrict__ pri,
                                    float* __restrict__ Wcat) {
  int gid = blockIdx.x * blockDim.x + threadIdx.x;
  const int total = 3 * 128 * 384;
  if (gid >= total) return;
  int l = gid / (128 * 384);
  int rem = gid - l * (128 * 384);
  int r = rem / 384;
  int j = rem - r * 384;
  float out;
  if (j >= 128 && j < 256) {
    out = Wq[(l * 128 + r) * 128 + (j - 128)];
  } else {
    int jj = j & 127;
    int hh = jj >> 4;
    int e = jj & 15;
    const float* W = (j < 128) ? Wk : Wv;
    const float* T = (j < 128) ? att : msg;
    float s = 0.f;
#pragma unroll
    for (int d = 0; d < 16; d++)
      s += W[(l * 128 + r) * 128 + hh * 16 + d] * T[((l * 8 + hh) * 16 + d) * 16 + e];
    if (j < 128) s *= pri[l * 8 + hh] * 0.25f;  // pri / sqrt(D=16)
    out = s;
  }
  Wcat[gid] = out;
}

// ---------------- transpose+split weights into packed B-fragment layout
__global__ void prep_bt_kernel(const float* __restrict__ W, ushort_t* __restrict__ Bh,
                               ushort_t* __restrict__ Bl, int K, int N, int Npad) {
  int g = blockIdx.x * blockDim.x + threadIdx.x;
  if (g >= Npad * K) return;
  int n = g / K, k = g - n * K;
  float v = (n < N) ? W[(size_t)k * N + n] : 0.f;
  ushort_t hh = f2bf(v);
  size_t o = packA(n, k, K);
  Bh[o] = hh;
  Bl[o] = f2bf(v - bf2f(hh));
}

// ---------------- split fp32 row-major [M][128] into packed A-fragment hi/lo (K=128)
__global__ void split_mat_kernel(const float* __restrict__ X, ushort_t* __restrict__ Xh,
                                 ushort_t* __restrict__ Xl, int total4) {
  int g = blockIdx.x * blockDim.x + threadIdx.x;
  if (g >= total4) return;
  int r = g >> 5, c = (g & 31) << 2;
  float4 v = *(const float4*)&X[(size_t)r * 128 + c];
  ushort_t h0 = f2bf(v.x), h1 = f2bf(v.y), h2 = f2bf(v.z), h3 = f2bf(v.w);
  size_t base = packA(r, c, 128);
  *(uint2*)(Xh + base) = make_uint2((unsigned)h0 | ((unsigned)h1 << 16),
                                    (unsigned)h2 | ((unsigned)h3 << 16));
  ushort_t l0 = f2bf(v.x - bf2f(h0)), l1 = f2bf(v.y - bf2f(h1));
  ushort_t l2 = f2bf(v.z - bf2f(h2)), l3 = f2bf(v.w - bf2f(h3));
  *(uint2*)(Xl + base) = make_uint2((unsigned)l0 | ((unsigned)l1 << 16),
                                    (unsigned)l2 | ((unsigned)l3 << 16));
}

// ---------------- CSR build by destination
__global__ void hist_kernel(const int* __restrict__ dst, int* __restrict__ deg, int E) {
  int g = blockIdx.x * blockDim.x + threadIdx.x;
  if (g < E) atomicAdd(&deg[dst[g]], 1);
}

__global__ void scan_kernel(const int* __restrict__ deg, int* __restrict__ offs,
                            int* __restrict__ cursor, int n) {
  __shared__ int sums[256];
  int t = threadIdx.x;
  int chunk = (n + 255) / 256;
  int begin = min(t * chunk, n);
  int end = min(begin + chunk, n);
  int s = 0;
  for (int i = begin; i < end; i++) s += deg[i];
  sums[t] = s;
  __syncthreads();
  for (int off = 1; off < 256; off <<= 1) {
    int v = (t >= off) ? sums[t - off] : 0;
    __syncthreads();
    sums[t] += v;
    __syncthreads();
  }
  int run = sums[t] - s;
  for (int i = begin; i < end; i++) {
    offs[i] = run;
    cursor[i] = run;
    run += deg[i];
  }
  if (t == 255) offs[n] = sums[255];
}

__global__ void scatter_kernel(const int* __restrict__ src, const int* __restrict__ dst,
                               const float* __restrict__ w, int* __restrict__ cursor,
                               int* __restrict__ elsrc, float* __restrict__ elw, int E) {
  int g = blockIdx.x * blockDim.x + threadIdx.x;
  if (g < E) {
    int d = dst[g];
    int p = atomicAdd(&cursor[d], 1);
    elsrc[p] = src[g];
    elw[p] = w[g];
  }
}

// ---------------- split-bf16 MFMA GEMM on packed fragments
// A: hi/lo packed [Mtiles][K/32][512]; Bt: hi/lo packed [Ntiles][K/32][512]
// epi: 0 bias+relu, 1 plain, 2 skip-mix(+relu opt), 3 bias+leaky(0.2)
// Cf: fp32 row-major out (optional); Chi/Clo: packed A-fragment out for next GEMM, Kout=N
__global__ __launch_bounds__(256) void gemm_mfma(
    const ushort_t* __restrict__ Ah, const ushort_t* __restrict__ Al,
    const ushort_t* __restrict__ Bth, const ushort_t* __restrict__ Btl,
    int M, int N, int K, int epi,
    const float* __restrict__ bias, const float* __restrict__ hold,
    const float* __restrict__ skipv, int relu,
    float* __restrict__ Cf, ushort_t* __restrict__ Chi, ushort_t* __restrict__ Clo,
    int Kout) {
  int tid = threadIdx.x;
  int wave = tid >> 6, lane = tid & 63;
  int l16 = lane & 15, q = lane >> 4;
  int m_base = blockIdx.x * 256 + wave * 64;
  int n_base = blockIdx.y * 64;
  int kc_count = K >> 5;

  floatx4 acc[4][4];
#pragma unroll
  for (int i = 0; i < 4; i++)
#pragma unroll
    for (int j = 0; j < 4; j++) acc[i][j] = (floatx4){0.f, 0.f, 0.f, 0.f};

  size_t a_base[4];
  bool tv[4];
#pragma unroll
  for (int mt = 0; mt < 4; mt++) {
    int tile = (m_base >> 4) + mt;
    tv[mt] = (tile * 16) < M;
    a_base[mt] = ((size_t)(tv[mt] ? tile : 0) * kc_count << 9) + lane * 8;
  }
  size_t b_base[4];
#pragma unroll
  for (int nt = 0; nt < 4; nt++)
    b_base[nt] = ((size_t)((n_base >> 4) + nt) * kc_count << 9) + lane * 8;

  const short8 zer = {0, 0, 0, 0, 0, 0, 0, 0};
  for (int kc = 0; kc < kc_count; kc++) {
    size_t koff = (size_t)kc << 9;
    short8 a_h[4], a_l[4], b_h[4], b_l[4];
#pragma unroll
    for (int nt = 0; nt < 4; nt++) {
      b_h[nt] = *(const short8*)(Bth + b_base[nt] + koff);
      b_l[nt] = *(const short8*)(Btl + b_base[nt] + koff);
    }
#pragma unroll
    for (int mt = 0; mt < 4; mt++) {
      if (tv[mt]) {
        a_h[mt] = *(const short8*)(Ah + a_base[mt] + koff);
        a_l[mt] = *(const short8*)(Al + a_base[mt] + koff);
      } else {
        a_h[mt] = zer;
        a_l[mt] = zer;
      }
    }
#pragma unroll
    for (int mt = 0; mt < 4; mt++)
#pragma unroll
      for (int nt = 0; nt < 4; nt++) {
        acc[mt][nt] = __builtin_amdgcn_mfma_f32_16x16x32_bf16(a_h[mt], b_h[nt], acc[mt][nt], 0, 0, 0);
        acc[mt][nt] = __builtin_amdgcn_mfma_f32_16x16x32_bf16(a_h[mt], b_l[nt], acc[mt][nt], 0, 0, 0);
        acc[mt][nt] = __builtin_amdgcn_mfma_f32_16x16x32_bf16(a_l[mt], b_h[nt], acc[mt][nt], 0, 0, 0);
      }
  }

  float alpha = 1.f, beta = 0.f;
  if (epi == 2) {
    float s = *skipv;
    alpha = 1.f / (1.f + __expf(-s));
    beta = 1.f - alpha;
  }
#pragma unroll
  for (int mt = 0; mt < 4; mt++) {
#pragma unroll
    for (int nt = 0; nt < 4; nt++) {
      int col = n_base + nt * 16 + l16;
      if (col >= N) continue;
      float bv = (epi == 0 || epi == 3) ? bias[col] : 0.f;
#pragma unroll
      for (int r = 0; r < 4; r++) {
        int row = m_base + mt * 16 + q * 4 + r;
        if (row >= M) continue;
        float v = acc[mt][nt][r];
        if (epi == 0) {
          v = fmaxf(v + bv, 0.f);
        } else if (epi == 2) {
          v = alpha * v + beta * hold[(size_t)row * N + col];
          if (relu) v = fmaxf(v, 0.f);
        } else if (epi == 3) {
          v += bv;
          v = v > 0.f ? v : 0.2f * v;
        }
        if (Cf) Cf[(size_t)row * N + col] = v;
        if (Chi) {
          ushort_t hh = f2bf(v);
          size_t o = packA(row, col, Kout);
          Chi[o] = hh;
          Clo[o] = f2bf(v - bf2f(hh));
        }
      }
    }
  }
}

// ---------------- per-destination online-softmax aggregation, 4-edge batched
// one wave per node; lane c2 in [0,32) covers channels 4c2..4c2+3; half = lane>>5 (0: kw, 1: mv)
__global__ __launch_bounds__(256) void edge_agg_kernel(
    const float* __restrict__ kqv, const int* __restrict__ offs,
    const int* __restrict__ elsrc, const float* __restrict__ elw,
    ushort_t* __restrict__ agg_hi, ushort_t* __restrict__ agg_lo, int n) {
  int wave = threadIdx.x >> 6;
  int lane = threadIdx.x & 63;
  int node = blockIdx.x * 4 + wave;
  if (node >= n) return;
  int c2 = lane & 31, half = lane >> 5;
  int ch = c2 * 4;
  float4 qv = *(const float4*)&kqv[(size_t)node * 384 + 128 + ch];
  size_t off_half = (size_t)(half ? 256 : 0) + ch;
  float m = -1e30f, s = 0.f;
  float ax = 0.f, ay = 0.f, az = 0.f, aw = 0.f;
  int beg = offs[node], end = offs[node + 1];
  int j = beg;
  for (; j + 4 <= end; j += 4) {
    int si0 = elsrc[j], si1 = elsrc[j + 1], si2 = elsrc[j + 2], si3 = elsrc[j + 3];
    float w0 = elw[j], w1 = elw[j + 1], w2 = elw[j + 2], w3 = elw[j + 3];
    float4 g0 = *(const float4*)&kqv[(size_t)si0 * 384 + off_half];
    float4 g1 = *(const float4*)&kqv[(size_t)si1 * 384 + off_half];
    float4 g2 = *(const float4*)&kqv[(size_t)si2 * 384 + off_half];
    float4 g3 = *(const float4*)&kqv[(size_t)si3 * 384 + off_half];
    float p0 = g0.x * qv.x + g0.y * qv.y + g0.z * qv.z + g0.w * qv.w;
    float p1 = g1.x * qv.x + g1.y * qv.y + g1.z * qv.z + g1.w * qv.w;
    float p2 = g2.x * qv.x + g2.y * qv.y + g2.z * qv.z + g2.w * qv.w;
    float p3 = g3.x * qv.x + g3.y * qv.y + g3.z * qv.z + g3.w * qv.w;
    p0 += __shfl_xor(p0, 1); p1 += __shfl_xor(p1, 1);
    p2 += __shfl_xor(p2, 1); p3 += __shfl_xor(p3, 1);
    p0 += __shfl_xor(p0, 2); p1 += __shfl_xor(p1, 2);
    p2 += __shfl_xor(p2, 2); p3 += __shfl_xor(p3, 2);
    float o0 = __shfl_xor(p0, 32), o1 = __shfl_xor(p1, 32);
    float o2 = __shfl_xor(p2, 32), o3 = __shfl_xor(p3, 32);
    if (half) { p0 = o0; p1 = o1; p2 = o2; p3 = o3; }
    float nm = fmaxf(fmaxf(fmaxf(p0, p1), fmaxf(p2, p3)), m);
    float sc = __expf(m - nm);
    float e0 = __expf(p0 - nm), e1 = __expf(p1 - nm);
    float e2 = __expf(p2 - nm), e3 = __expf(p3 - nm);
    s = s * sc + (e0 + e1) + (e2 + e3);
    m = nm;
    if (half) {
      float f0 = e0 * w0, f1 = e1 * w1, f2 = e2 * w2, f3 = e3 * w3;
      ax = ax * sc + f0 * g0.x + f1 * g1.x + f2 * g2.x + f3 * g3.x;
      ay = ay * sc + f0 * g0.y + f1 * g1.y + f2 * g2.y + f3 * g3.y;
      az = az * sc + f0 * g0.z + f1 * g1.z + f2 * g2.z + f3 * g3.z;
      aw = aw * sc + f0 * g0.w + f1 * g1.w + f2 * g2.w + f3 * g3.w;
    }
  }
  for (; j < end; j++) {
    int si = elsrc[j];
    float w = elw[j];
    float4 g = *(const float4*)&kqv[(size_t)si * 384 + off_half];
    float p = g.x * qv.x + g.y * qv.y + g.z * qv.z + g.w * qv.w;
    p += __shfl_xor(p, 1);
    p += __shfl_xor(p, 2);
    float po = __shfl_xor(p, 32);
    if (half) p = po;
    float nm = fmaxf(m, p);
    float sc = __expf(m - nm);
    float e = __expf(p - nm);
    s = s * sc + e;
    m = nm;
    if (half) {
      float ew = e * w;
      ax = ax * sc + ew * g.x;
      ay = ay * sc + ew * g.y;
      az = az * sc + ew * g.z;
      aw = aw * sc + ew * g.w;
    }
  }
  if (half) {
    float inv = (s > 0.f) ? 1.f / s : 0.f;
    float v0 = ax * inv, v1 = ay * inv, v2 = az * inv, v3 = aw * inv;
    ushort_t h0 = f2bf(v0), h1 = f2bf(v1), h2 = f2bf(v2), h3 = f2bf(v3);
    size_t base = packA(node, ch, 128);
    *(uint2*)(agg_hi + base) = make_uint2((unsigned)h0 | ((unsigned)h1 << 16),
                                          (unsigned)h2 | ((unsigned)h3 << 16));
    ushort_t l0 = f2bf(v0 - bf2f(h0)), l1 = f2bf(v1 - bf2f(h1));
    ushort_t l2 = f2bf(v2 - bf2f(h2)), l3 = f2bf(v3 - bf2f(h3));
    *(uint2*)(agg_lo + base) = make_uint2((unsigned)l0 | ((unsigned)l1 << 16),
                                          (unsigned)l2 | ((unsigned)l3 << 16));
  }
}

// ---------------- predictor helpers
__global__ void zbuild_kernel(const float* __restrict__ hsrc, const int* __restrict__ ia,
                              const int* __restrict__ ib, ushort_t* __restrict__ Zh,
                              ushort_t* __restrict__ Zl, int P) {
  int g = blockIdx.x * blockDim.x + threadIdx.x;
  if (g >= P * 32) return;
  int r = g >> 5, c = (g & 31) << 2;
  float4 va = *(const float4*)&hsrc[(size_t)ia[r] * 128 + c];
  float4 vb = *(const float4*)&hsrc[(size_t)ib[r] * 128 + c];
  float z0 = va.x * vb.x, z1 = va.y * vb.y, z2 = va.z * vb.z, z3 = va.w * vb.w;
  ushort_t h0 = f2bf(z0), h1 = f2bf(z1), h2 = f2bf(z2), h3 = f2bf(z3);
  size_t base = packA(r, c, 128);
  *(uint2*)(Zh + base) =
      make_uint2((unsigned)h0 | ((unsigned)h1 << 16), (unsigned)h2 | ((unsigned)h3 << 16));
  ushort_t l0 = f2bf(z0 - bf2f(h0)), l1 = f2bf(z1 - bf2f(h1));
  ushort_t l2 = f2bf(z2 - bf2f(h2)), l3 = f2bf(z3 - bf2f(h3));
  *(uint2*)(Zl + base) =
      make_uint2((unsigned)l0 | ((unsigned)l1 << 16), (unsigned)l2 | ((unsigned)l3 << 16));
}

__global__ void final_dot_kernel(const float* __restrict__ T2, const float* __restrict__ W3,
                                 const float* __restrict__ b3, float* __restrict__ outp, int P) {
  int r = blockIdx.x * blockDim.x + threadIdx.x;
  if (r >= P) return;
  float acc = b3[0];
  const float* row = T2 + (size_t)r * 32;
#pragma unroll
  for (int k = 0; k < 32; k++) acc += row[k] * W3[k];
  outp[r] = acc;
}

extern "C" void kernel_launch(void* const* d_in, const int* in_sizes, int n_in,
                              void* d_out, int out_size, void* d_ws, size_t ws_size,
                              hipStream_t stream) {
  const float* x        = (const float*)d_in[0];
  const int*   edge_src = (const int*)d_in[1];
  const int*   edge_dst = (const int*)d_in[2];
  const float* edge_w   = (const float*)d_in[3];
  const int*   pos_src  = (const int*)d_in[4];
  const int*   pos_dst  = (const int*)d_in[5];
  const int*   neg_src  = (const int*)d_in[6];
  const int*   neg_dst  = (const int*)d_in[7];
  const float* W_in     = (const float*)d_in[8];
  const float* b_in     = (const float*)d_in[9];
  const float* Wk       = (const float*)d_in[10];
  const float* Wq       = (const float*)d_in[11];
  const float* Wv       = (const float*)d_in[12];
  const float* att_w    = (const float*)d_in[13];
  const float* msg_w    = (const float*)d_in[14];
  const float* pri      = (const float*)d_in[15];
  const float* Wa       = (const float*)d_in[16];
  const float* skip     = (const float*)d_in[17];
  const float* W1       = (const float*)d_in[18];
  const float* b1       = (const float*)d_in[19];
  const float* W2       = (const float*)d_in[20];
  const float* b2       = (const float*)d_in[21];
  const float* W3       = (const float*)d_in[22];
  const float* b3       = (const float*)d_in[23];
  float* out = (float*)d_out;

  // ---- workspace layout (bytes), ~162 MB, heavy aliasing
  char* W = (char*)d_ws;
  float*    kqv    = (float*)(W + 0);              // 76,800,000
  float*    h      = (float*)(W + 76800000);       // 25,600,000
  ushort_t* h_hi   = (ushort_t*)(W + 102400000);   // 12,800,000 (packed A-frag)
  ushort_t* h_lo   = (ushort_t*)(W + 115200000);   // 12,800,000
  ushort_t* s1_hi  = (ushort_t*)(W + 128000000);   // 12,800,000 (x -> agg -> T1, packed)
  ushort_t* s1_lo  = (ushort_t*)(W + 140800000);   // 12,800,000
  float*    Wcat   = (float*)(W + 153600000);      // 589,824
  ushort_t* Wint_h = (ushort_t*)(W + 154189824);   // 32,768
  ushort_t* Wint_l = (ushort_t*)(W + 154222592);   // 32,768
  ushort_t* Wcat_h = (ushort_t*)(W + 154255360);   // 294,912
  ushort_t* Wcat_l = (ushort_t*)(W + 154550272);   // 294,912
  ushort_t* Wa_h   = (ushort_t*)(W + 154845184);   // 98,304
  ushort_t* Wa_l   = (ushort_t*)(W + 154943488);   // 98,304
  ushort_t* W1_h   = (ushort_t*)(W + 155041792);   // 16,384
  ushort_t* W1_l   = (ushort_t*)(W + 155058176);   // 16,384
  ushort_t* W2_h   = (ushort_t*)(W + 155074560);   // 8,192
  ushort_t* W2_l   = (ushort_t*)(W + 155082752);   // 8,192
  float*    elw    = (float*)(W + 155100000);      // 3,200,000
  int*      elsrc  = (int*)(W + 158300000);        // 3,200,000
  int*      deg    = (int*)(W + 161500000);        // 200,000
  int*      offs   = (int*)(W + 161700000);        // 200,016
  int*      cursor = (int*)(W + 161900016);        // 200,000
  // aliases
  ushort_t* Z_h  = (ushort_t*)(W + 0);             // over kqv (dead by predictor)
  ushort_t* Z_l  = (ushort_t*)(W + 25600000);
  float*    T2   = h;                              // h dead by predictor
  ushort_t* agg_hi = s1_hi; ushort_t* agg_lo = s1_lo;
  ushort_t* T1_h = s1_hi;  ushort_t* T1_l = s1_lo;
  float* hfinal = out + 2 * N_PAIRS;

  hipMemsetAsync(deg, 0, N_NODES * sizeof(int), stream);
  fold_weights_kernel<<<(3 * 128 * 384 + 255) / 256, 256, 0, stream>>>(
      Wk, Wq, Wv, att_w, msg_w, pri, Wcat);
  // weight transpose+split into packed B-fragment layout
  prep_bt_kernel<<<(128 * 128 + 255) / 256, 256, 0, stream>>>(W_in, Wint_h, Wint_l, 128, 128, 128);
  for (int l = 0; l < 3; l++) {
    prep_bt_kernel<<<(384 * 128 + 255) / 256, 256, 0, stream>>>(
        Wcat + l * 49152, Wcat_h + l * 49152, Wcat_l + l * 49152, 128, 384, 384);
    prep_bt_kernel<<<(128 * 128 + 255) / 256, 256, 0, stream>>>(
        Wa + l * 16384, Wa_h + l * 16384, Wa_l + l * 16384, 128, 128, 128);
  }
  prep_bt_kernel<<<(64 * 128 + 255) / 256, 256, 0, stream>>>(W1, W1_h, W1_l, 128, 64, 64);
  prep_bt_kernel<<<(64 * 64 + 255) / 256, 256, 0, stream>>>(W2, W2_h, W2_l, 64, 32, 64);
  // x split into packed A-fragments (s1 reused as agg later; input GEMM consumes x first)
  split_mat_kernel<<<(N_NODES * 32 + 255) / 256, 256, 0, stream>>>(x, s1_hi, s1_lo, N_NODES * 32);
  // CSR
  hist_kernel<<<(N_EDGES + 255) / 256, 256, 0, stream>>>(edge_dst, deg, N_EDGES);
  scan_kernel<<<1, 256, 0, stream>>>(deg, offs, cursor, N_NODES);
  scatter_kernel<<<(N_EDGES + 255) / 256, 256, 0, stream>>>(
      edge_src, edge_dst, edge_w, cursor, elsrc, elw, N_EDGES);

  // input projection: h = relu(x @ W_in + b_in), emit fp32 + packed hi/lo
  gemm_mfma<<<dim3(196, 2), 256, 0, stream>>>(s1_hi, s1_lo, Wint_h, Wint_l,
                                              N_NODES, 128, 128, 0,
                                              b_in, nullptr, nullptr, 0,
                                              h, h_hi, h_lo, 128);

  for (int l = 0; l < 3; l++) {
    gemm_mfma<<<dim3(196, 6), 256, 0, stream>>>(h_hi, h_lo,
                                                Wcat_h + l * 49152, Wcat_l + l * 49152,
                                                N_NODES, 384, 128, 1,
                                                nullptr, nullptr, nullptr, 0,
                                                kqv, nullptr, nullptr, 0);
    edge_agg_kernel<<<(N_NODES + 3) / 4, 256, 0, stream>>>(kqv, offs, elsrc, elw,
                                                           agg_hi, agg_lo, N_NODES);
    int last = (l == 2);
    gemm_mfma<<<dim3(196, 2), 256, 0, stream>>>(agg_hi, agg_lo,
                                                Wa_h + l * 16384, Wa_l + l * 16384,
                                                N_NODES, 128, 128, 2,
                                                nullptr, h, skip + l, last ? 0 : 1,
                                                last ? hfinal : h,
                                                last ? nullptr : h_hi,
                                                last ? nullptr : h_lo, 128);
  }

  for (int half = 0; half < 2; half++) {
    const int* ia = half ? neg_src : pos_src;
    const int* ib = half ? neg_dst : pos_dst;
    zbuild_kernel<<<(N_PAIRS * 32 + 255) / 256, 256, 0, stream>>>(hfinal, ia, ib,
                                                                  Z_h, Z_l, N_PAIRS);
    gemm_mfma<<<dim3(391, 1), 256, 0, stream>>>(Z_h, Z_l, W1_h, W1_l,
                                                N_PAIRS, 64, 128, 3,
                                                b1, nullptr, nullptr, 0,
                                                nullptr, T1_h, T1_l, 64);
    gemm_mfma<<<dim3(391, 1), 256, 0, stream>>>(T1_h, T1_l, W2_h, W2_l,
                                                N_PAIRS, 32, 64, 3,
                                                b2, nullptr, nullptr, 0,
                                                T2, nullptr, nullptr, 0);
    final_dot_kernel<<<(N_PAIRS + 255) / 256, 256, 0, stream>>>(
        T2, W3, b3, out + half * N_PAIRS, N_PAIRS);
  }
}